// Round 11
// baseline (215.934 us; speedup 1.0000x reference)
//
#include <hip/hip_runtime.h>
#include <hip/hip_bf16.h>
#include <stdint.h>

#define B_ 32
#define T_ 128
#define S_ 2048
#define D_ 1024

typedef float floatx4 __attribute__((ext_vector_type(4)));
typedef float f32x4 __attribute__((ext_vector_type(4)));
typedef unsigned short u16x4 __attribute__((ext_vector_type(4)));
typedef unsigned short u16x8 __attribute__((ext_vector_type(8)));
typedef __bf16 bf16x8 __attribute__((ext_vector_type(8)));

__device__ __forceinline__ unsigned short f2bf(float x){
  __hip_bfloat16 h = __float2bfloat16(x);
  return __builtin_bit_cast(unsigned short, h);
}
__device__ __forceinline__ float bf2f(unsigned short u){
  __hip_bfloat16 h = __builtin_bit_cast(__hip_bfloat16, u);
  return __bfloat162float(h);
}
__device__ __forceinline__ f32x4 mfma16(u16x8 a, u16x8 b, f32x4 c){
  return __builtin_amdgcn_mfma_f32_16x16x32_bf16(
      __builtin_bit_cast(bf16x8, a), __builtin_bit_cast(bf16x8, b), c, 0, 0, 0);
}

// ---- k_align helpers (plain functions, no macros) --------------------------
__device__ __forceinline__ void load_tile(
    const float* Ag, const float* Bg, int k0, int r0, int c40, int r1,
    floatx4 (&ra)[2], floatx4 (&rb)[2])
{
  ra[0] = *(const floatx4*)(Ag + (size_t)r0 * D_ + k0 + c40);
  ra[1] = *(const floatx4*)(Ag + (size_t)r1 * D_ + k0 + c40);
  rb[0] = *(const floatx4*)(Bg + (size_t)r0 * D_ + k0 + c40);
  rb[1] = *(const floatx4*)(Bg + (size_t)r1 * D_ + k0 + c40);
}

__device__ __forceinline__ void store_cvt(
    unsigned short (*buf)[128][32],          // 4 panels of one LDS buffer
    const floatx4 (&ra)[2], const floatx4 (&rb)[2],
    int r0, int sw0, int r1, int sw1)
{
  u16x4 ah, al, bh, bl;
  #pragma unroll
  for (int i = 0; i < 4; i++) {
    unsigned short h = f2bf(ra[0][i]); float hf = bf2f(h);
    ah[i] = h; al[i] = f2bf(ra[0][i] - hf);
    h = f2bf(rb[0][i]); hf = bf2f(h);
    bh[i] = h; bl[i] = f2bf(rb[0][i] - hf);
  }
  *(u16x4*)&buf[0][r0][sw0] = ah;
  *(u16x4*)&buf[1][r0][sw0] = al;
  *(u16x4*)&buf[2][r0][sw0] = bh;
  *(u16x4*)&buf[3][r0][sw0] = bl;
  #pragma unroll
  for (int i = 0; i < 4; i++) {
    unsigned short h = f2bf(ra[1][i]); float hf = bf2f(h);
    ah[i] = h; al[i] = f2bf(ra[1][i] - hf);
    h = f2bf(rb[1][i]); hf = bf2f(h);
    bh[i] = h; bl[i] = f2bf(rb[1][i] - hf);
  }
  *(u16x4*)&buf[0][r1][sw1] = ah;
  *(u16x4*)&buf[1][r1][sw1] = al;
  *(u16x4*)&buf[2][r1][sw1] = bh;
  *(u16x4*)&buf[3][r1][sw1] = bl;
}

__device__ __forceinline__ void mfma_step(
    unsigned short (*buf)[128][32], int wr, int wc, int lane,
    f32x4 (&acc)[4][2])
{
  const int kb = (lane >> 4) << 3;
  u16x8 a_h[4], a_l[4], b_h[2], b_l[2];
  #pragma unroll
  for (int m = 0; m < 4; m++) {
    int r = wr * 64 + m * 16 + (lane & 15);
    int kbs = (((kb >> 3) ^ ((r >> 1) & 3)) << 3);
    a_h[m] = *(const u16x8*)&buf[0][r][kbs];
    a_l[m] = *(const u16x8*)&buf[1][r][kbs];
  }
  #pragma unroll
  for (int n = 0; n < 2; n++) {
    int r = wc * 32 + n * 16 + (lane & 15);
    int kbs = (((kb >> 3) ^ ((r >> 1) & 3)) << 3);
    b_h[n] = *(const u16x8*)&buf[2][r][kbs];
    b_l[n] = *(const u16x8*)&buf[3][r][kbs];
  }
  #pragma unroll
  for (int m = 0; m < 4; m++)
    #pragma unroll
    for (int n = 0; n < 2; n++) {
      acc[m][n] = mfma16(a_h[m], b_h[n], acc[m][n]);
      acc[m][n] = mfma16(a_h[m], b_l[n], acc[m][n]);
      acc[m][n] = mfma16(a_l[m], b_h[n], acc[m][n]);
    }
}

// ---------------------------------------------------------------------------
// K1: logits[b][t][s] = sum_d src[b][t][d] * mb[b][s][d]
// R9-verified dbuf base (RNE hi/lo split x 3 MFMA, one barrier/iter, XOR
// chunk swizzle, 64 KB LDS -> 2 blocks/CU) + 2-DEEP register prefetch:
//   entry(it):  buf[it&1] = tile it (converted);  regs[cur] = tile it+1
//   body(it):   load tile it+2 -> regs[other]     (other's tile dead)
//               MFMA  <- buf[it&1]
//               convert regs[cur] -> buf[(it+1)&1]
//               barrier
// Load->use distance now spans a full iteration (> HBM latency).
// Loop unrolled 2x so the A/B register sets are statically named.
// ---------------------------------------------------------------------------
__global__ __launch_bounds__(512, 4) void k_align(
    const float* __restrict__ src, const float* __restrict__ mb,
    float* __restrict__ logits)
{
  __shared__ unsigned short SH[2][4][128][32];
  const int b = blockIdx.x, sblk = blockIdx.y;
  const int tid = threadIdx.x, lane = tid & 63, wave = tid >> 6;
  const int wr = wave >> 2, wc = wave & 3;
  const float* Ag = src + (size_t)b * T_ * D_;
  const float* Bg = mb + (size_t)b * S_ * D_ + (size_t)sblk * 128 * D_;

  f32x4 acc[4][2];
  #pragma unroll
  for (int m = 0; m < 4; m++)
    #pragma unroll
    for (int n = 0; n < 2; n++) acc[m][n] = (f32x4){0.f, 0.f, 0.f, 0.f};

  const int r0 = tid >> 3;
  const int c40 = (tid & 7) * 4;
  const int sw0 = ((((c40 >> 3) ^ ((r0 >> 1) & 3)) << 3) | (c40 & 7));
  const int r1 = r0 + 64;
  const int sw1 = ((((c40 >> 3) ^ ((r1 >> 1) & 3)) << 3) | (c40 & 7));

  floatx4 raA[2], rbA[2], raB[2], rbB[2];
  // prologue: tile0 -> B set (convert now), tile1 -> A set (convert in it=0)
  load_tile(Ag, Bg, 0,  r0, c40, r1, raB, rbB);
  load_tile(Ag, Bg, 32, r0, c40, r1, raA, rbA);
  store_cvt(SH[0], raB, rbB, r0, sw0, r1, sw1);
  __syncthreads();

  for (int itp = 0; itp < 16; ++itp) {
    const int it0 = itp * 2;
    // ---- even iter it0: buf0 = tile it0, A = tile it0+1 ----
    if (it0 + 2 < 32)
      load_tile(Ag, Bg, (it0 + 2) * 32, r0, c40, r1, raB, rbB);
    mfma_step(SH[0], wr, wc, lane, acc);
    store_cvt(SH[1], raA, rbA, r0, sw0, r1, sw1);   // tile it0+1 (<=31)
    __syncthreads();
    // ---- odd iter it0+1: buf1 = tile it0+1, B = tile it0+2 ----
    if (it0 + 3 < 32)
      load_tile(Ag, Bg, (it0 + 3) * 32, r0, c40, r1, raA, rbA);
    mfma_step(SH[1], wr, wc, lane, acc);
    if (it0 + 2 < 32)
      store_cvt(SH[0], raB, rbB, r0, sw0, r1, sw1); // tile it0+2
    __syncthreads();
  }

  #pragma unroll
  for (int m = 0; m < 4; m++)
    #pragma unroll
    for (int n = 0; n < 2; n++)
      #pragma unroll
      for (int j = 0; j < 4; j++) {
        int t = wr * 64 + m * 16 + ((lane >> 4) << 2) + j;
        int s = sblk * 128 + wc * 32 + n * 16 + (lane & 15);
        logits[((size_t)b * T_ + t) * S_ + s] = acc[m][n][j];
      }
}

// ---------------------------------------------------------------------------
// K2: masked softmax per (b,t) row. Writes out1[t][b][s] fp32 (output) and
// pbf[b][t][s] BF16 handoff to K3.  (R10-verified, unchanged)
// ---------------------------------------------------------------------------
__global__ __launch_bounds__(256) void k_softmax(
    const float* __restrict__ logits, const int* __restrict__ lens,
    float* __restrict__ out1, unsigned short* __restrict__ pbf)
{
  const int bt = blockIdx.x;
  const int b = bt >> 7, t = bt & 127;
  const int probe = lens[1];               // 0 iff int64 layout (lens>=1)
  const int len = (probe == 0) ? lens[2 * b] : lens[b];
  const float* row = logits + (size_t)bt * S_;
  const int tid = threadIdx.x, lane = tid & 63, wave = tid >> 6;

  floatx4 v[2];
  float mx = -3.0e38f;
  #pragma unroll
  for (int j = 0; j < 2; j++) {
    int f4 = tid + 256 * j;
    v[j] = *(const floatx4*)(row + f4 * 4);
    #pragma unroll
    for (int i = 0; i < 4; i++) {
      int s = f4 * 4 + i;
      if (s < len) mx = fmaxf(mx, v[j][i]);
    }
  }
  #pragma unroll
  for (int off = 1; off < 64; off <<= 1) mx = fmaxf(mx, __shfl_xor(mx, off));
  __shared__ float red[8];
  if (lane == 0) red[wave] = mx;
  __syncthreads();
  mx = fmaxf(fmaxf(red[0], red[1]), fmaxf(red[2], red[3]));

  float sum = 0.f;
  floatx4 e[2];
  #pragma unroll
  for (int j = 0; j < 2; j++) {
    int f4 = tid + 256 * j;
    #pragma unroll
    for (int i = 0; i < 4; i++) {
      int s = f4 * 4 + i;
      float ee = (s < len) ? __expf(v[j][i] - mx) : 0.f;
      e[j][i] = ee; sum += ee;
    }
  }
  #pragma unroll
  for (int off = 1; off < 64; off <<= 1) sum += __shfl_xor(sum, off);
  if (lane == 0) red[4 + wave] = sum;
  __syncthreads();
  sum = red[4] + red[5] + red[6] + red[7];
  const float inv = 1.0f / sum;

  float* orow = out1 + ((size_t)t * B_ + b) * S_;
  unsigned short* prow = pbf + (size_t)bt * S_;
  #pragma unroll
  for (int j = 0; j < 2; j++) {
    int f4 = tid + 256 * j;
    floatx4 o;
    u16x4 pk;
    #pragma unroll
    for (int i = 0; i < 4; i++) { o[i] = e[j][i] * inv; pk[i] = f2bf(o[i]); }
    *(floatx4*)(orow + f4 * 4) = o;   // output, [t][b][s] fp32
    *(u16x4*)(prow + f4 * 4) = pk;    // handoff, [b][t][s] bf16
  }
}

// ---------------------------------------------------------------------------
// K3: c[b][t][d] = sum_s p[b][t][s] * mb[b][s][d].  (R10-verified, unchanged)
// ---------------------------------------------------------------------------
__global__ __launch_bounds__(256, 2) void k_pv(
    const unsigned short* __restrict__ pbf, const float* __restrict__ mb,
    float* __restrict__ cout)
{
  __shared__ unsigned short As[128][72];   // [t][s]
  __shared__ unsigned short BsT[64][72];   // [d][s]
  const int b = blockIdx.x, dblk = blockIdx.y;   // dblk: 64 d each
  const int tid = threadIdx.x, lane = tid & 63, wave = tid >> 6;
  const int wr = wave >> 1, wc = wave & 1;       // 2x2 wave grid
  const unsigned short* Pg = pbf + (size_t)b * T_ * S_;
  const float* Bg = mb + (size_t)b * S_ * D_ + dblk * 64;

  f32x4 acc[4][2];
  #pragma unroll
  for (int m = 0; m < 4; m++)
    #pragma unroll
    for (int n = 0; n < 2; n++) acc[m][n] = (f32x4){0.f, 0.f, 0.f, 0.f};

  const int gs = tid & 15, gd = tid >> 4;  // transpose group: 4s x 4d
  const int s0 = gs * 4, d0 = gd * 4;      // both 0..60

  u16x8 ra[4];
  floatx4 rb[4];
  #pragma unroll
  for (int j = 0; j < 4; j++) {
    int g = tid + 256 * j;
    int row = g >> 3, c8 = (g & 7) * 8;
    ra[j] = *(const u16x8*)(Pg + (size_t)row * S_ + c8);
  }
  #pragma unroll
  for (int j = 0; j < 4; j++)
    rb[j] = *(const floatx4*)(Bg + (size_t)(s0 + j) * D_ + d0);

  for (int k0 = 0; k0 < S_; k0 += 64) {
    #pragma unroll
    for (int j = 0; j < 4; j++) {
      int g = tid + 256 * j;
      int row = g >> 3, c8 = (g & 7) * 8;
      *(u16x8*)&As[row][c8] = ra[j];
    }
    #pragma unroll
    for (int jj = 0; jj < 4; jj++) {
      u16x4 w = { f2bf(rb[0][jj]), f2bf(rb[1][jj]), f2bf(rb[2][jj]), f2bf(rb[3][jj]) };
      *(u16x4*)&BsT[d0 + jj][s0] = w;
    }
    __syncthreads();
    if (k0 + 64 < S_) {
      #pragma unroll
      for (int j = 0; j < 4; j++) {
        int g = tid + 256 * j;
        int row = g >> 3, c8 = (g & 7) * 8;
        ra[j] = *(const u16x8*)(Pg + (size_t)row * S_ + (k0 + 64) + c8);
      }
      #pragma unroll
      for (int j = 0; j < 4; j++)
        rb[j] = *(const floatx4*)(Bg + (size_t)(k0 + 64 + s0 + j) * D_ + d0);
    }
    #pragma unroll
    for (int kk = 0; kk < 2; kk++) {
      int kb = kk * 32 + ((lane >> 4) << 3);
      u16x8 a[4], bb[2];
      #pragma unroll
      for (int m = 0; m < 4; m++)
        a[m] = *(const u16x8*)&As[wr * 64 + m * 16 + (lane & 15)][kb];
      #pragma unroll
      for (int n = 0; n < 2; n++)
        bb[n] = *(const u16x8*)&BsT[wc * 32 + n * 16 + (lane & 15)][kb];
      #pragma unroll
      for (int m = 0; m < 4; m++)
        #pragma unroll
        for (int n = 0; n < 2; n++)
          acc[m][n] = mfma16(a[m], bb[n], acc[m][n]);
    }
    __syncthreads();
  }
  #pragma unroll
  for (int m = 0; m < 4; m++)
    #pragma unroll
    for (int n = 0; n < 2; n++)
      #pragma unroll
      for (int j = 0; j < 4; j++) {
        int t = wr * 64 + m * 16 + ((lane >> 4) << 2) + j;
        int d = dblk * 64 + wc * 32 + n * 16 + (lane & 15);
        cout[((size_t)b * T_ + t) * D_ + d] = acc[m][n][j];
      }
}

// ---------------------------------------------------------------------------
// K4: attn_h[t][b][n] = tanh( sum_k [c,src][b][t][k] * W[n][k] )
// (R8/R10-verified, unchanged)
// ---------------------------------------------------------------------------
__global__ __launch_bounds__(256, 2) void k_proj(
    const float* __restrict__ cbuf, const float* __restrict__ src,
    const float* __restrict__ w, float* __restrict__ out0)
{
  __shared__ unsigned short Ah[128][72];   // [t][k]
  __shared__ unsigned short Bh[64][72];    // [n][k]
  const int b = blockIdx.x, nblk = blockIdx.y;   // nblk: 64 n each
  const int tid = threadIdx.x, lane = tid & 63, wave = tid >> 6;
  const int wr = wave >> 1, wc = wave & 1;
  const float* Ca = cbuf + (size_t)b * T_ * D_;
  const float* Sa = src + (size_t)b * T_ * D_;

  f32x4 acc[4][2];
  #pragma unroll
  for (int m = 0; m < 4; m++)
    #pragma unroll
    for (int n = 0; n < 2; n++) acc[m][n] = (f32x4){0.f, 0.f, 0.f, 0.f};

  floatx4 ra[8], rb[4];
  #pragma unroll
  for (int j = 0; j < 8; j++) {
    int f4 = tid + 256 * j;
    int row = f4 >> 4, c4 = (f4 & 15) * 4;
    ra[j] = *(const floatx4*)(Ca + (size_t)row * D_ + c4);
  }
  #pragma unroll
  for (int j = 0; j < 4; j++) {
    int f4 = tid + 256 * j;
    int row = f4 >> 4, c4 = (f4 & 15) * 4;
    rb[j] = *(const floatx4*)(w + (size_t)(nblk * 64 + row) * (2 * D_) + c4);
  }

  for (int k0 = 0; k0 < 2 * D_; k0 += 64) {
    #pragma unroll
    for (int j = 0; j < 8; j++) {
      int f4 = tid + 256 * j;
      int row = f4 >> 4, c4 = (f4 & 15) * 4;
      u16x4 ah;
      #pragma unroll
      for (int i = 0; i < 4; i++) ah[i] = f2bf(ra[j][i]);
      *(u16x4*)&Ah[row][c4] = ah;
    }
    #pragma unroll
    for (int j = 0; j < 4; j++) {
      int f4 = tid + 256 * j;
      int row = f4 >> 4, c4 = (f4 & 15) * 4;
      u16x4 bh;
      #pragma unroll
      for (int i = 0; i < 4; i++) bh[i] = f2bf(rb[j][i]);
      *(u16x4*)&Bh[row][c4] = bh;
    }
    __syncthreads();
    if (k0 + 64 < 2 * D_) {
      int kn = k0 + 64;
      const float* Asrc = (kn < D_) ? (Ca + kn) : (Sa + (kn - D_));
      #pragma unroll
      for (int j = 0; j < 8; j++) {
        int f4 = tid + 256 * j;
        int row = f4 >> 4, c4 = (f4 & 15) * 4;
        ra[j] = *(const floatx4*)(Asrc + (size_t)row * D_ + c4);
      }
      #pragma unroll
      for (int j = 0; j < 4; j++) {
        int f4 = tid + 256 * j;
        int row = f4 >> 4, c4 = (f4 & 15) * 4;
        rb[j] = *(const floatx4*)(w + (size_t)(nblk * 64 + row) * (2 * D_) + kn + c4);
      }
    }
    #pragma unroll
    for (int kk = 0; kk < 2; kk++) {
      int kb = kk * 32 + ((lane >> 4) << 3);
      u16x8 a[4], bb[2];
      #pragma unroll
      for (int m = 0; m < 4; m++)
        a[m] = *(const u16x8*)&Ah[wr * 64 + m * 16 + (lane & 15)][kb];
      #pragma unroll
      for (int n = 0; n < 2; n++)
        bb[n] = *(const u16x8*)&Bh[wc * 32 + n * 16 + (lane & 15)][kb];
      #pragma unroll
      for (int m = 0; m < 4; m++)
        #pragma unroll
        for (int n = 0; n < 2; n++)
          acc[m][n] = mfma16(a[m], bb[n], acc[m][n]);
    }
    __syncthreads();
  }
  #pragma unroll
  for (int m = 0; m < 4; m++)
    #pragma unroll
    for (int n = 0; n < 2; n++)
      #pragma unroll
      for (int j = 0; j < 4; j++) {
        int t = wr * 64 + m * 16 + ((lane >> 4) << 2) + j;
        int d = nblk * 64 + wc * 32 + n * 16 + (lane & 15);
        out0[(size_t)t * (B_ * D_) + (size_t)b * D_ + d] = tanhf(acc[m][n][j]);
      }
}

extern "C" void kernel_launch(void* const* d_in, const int* in_sizes, int n_in,
                              void* d_out, int out_size, void* d_ws, size_t ws_size,
                              hipStream_t stream) {
  const float* src = (const float*)d_in[0];   // [B][T][D]
  const float* mb  = (const float*)d_in[1];   // [B][S][D]
  const float* w   = (const float*)d_in[2];   // [D][2D]
  const int*   len = (const int*)d_in[3];     // [B]

  float* out0 = (float*)d_out;                       // attn_h [T][B][D]
  float* out1 = out0 + (size_t)T_ * B_ * D_;         // align  [T][B][S]

  float* logits = (float*)d_ws;                        // [B][T][S] fp32
  float* cbuf   = logits + (size_t)B_ * T_ * S_;       // [B][T][D] fp32
  unsigned short* pbf =
      (unsigned short*)(cbuf + (size_t)B_ * T_ * D_);  // [B][T][S] bf16

  k_align  <<<dim3(B_, S_ / 128), 512, 0, stream>>>(src, mb, logits);
  k_softmax<<<dim3(B_ * T_),      256, 0, stream>>>(logits, len, out1, pbf);
  k_pv     <<<dim3(B_, D_ / 64),  256, 0, stream>>>(pbf, mb, cbuf);
  k_proj   <<<dim3(B_, D_ / 64),  256, 0, stream>>>(cbuf, src, w, out0);
}